// Round 1
// baseline (2032.142 us; speedup 1.0000x reference)
//
#include <hip/hip_runtime.h>

#define HDIM 20
#define NSTEP 5
#define M 2

typedef float v2f __attribute__((ext_vector_type(2)));

__device__ __forceinline__ float fsig(float x) {
    // 1/(1+e^-x) via v_exp_f32 (2^x) + v_rcp_f32
    return __builtin_amdgcn_rcpf(1.0f + __builtin_amdgcn_exp2f(-1.4426950408889634f * x));
}
__device__ __forceinline__ float ftanh(float x) {
    // 1 - 2/(e^{2x}+1); saturates correctly at +/-inf
    return 1.0f - 2.0f * __builtin_amdgcn_rcpf(__builtin_amdgcn_exp2f(2.8853900817779268f * x) + 1.0f);
}
__device__ __forceinline__ v2f pkfma(v2f a, v2f b, v2f c) {
    return __builtin_elementwise_fma(a, b, c);   // -> v_pk_fma_f32
}
__device__ __forceinline__ float f4get(const float4& v, int q) {
    return q == 0 ? v.x : q == 1 ? v.y : q == 2 ? v.z : v.w;   // q is compile-time
}
__device__ __forceinline__ void f4set(float4& v, int q, float s) {
    if (q == 0) v.x = s; else if (q == 1) v.y = s; else if (q == 2) v.z = s; else v.w = s;
}

__global__ __launch_bounds__(256) void navi_kernel(
    const float* __restrict__ inp,     // [B]
    const float* __restrict__ hidden,  // [2,B,H]
    const float* __restrict__ cell,    // [2,B,H]
    const float* __restrict__ W_ih1,   // [80,2]
    const float* __restrict__ W_hh1,   // [80,20]
    const float* __restrict__ b_ih1,   // [80]
    const float* __restrict__ b_hh1,   // [80]
    const float* __restrict__ W_ih2,   // [80,20]
    const float* __restrict__ W_hh2,   // [80,20]
    const float* __restrict__ b_ih2,   // [80]
    const float* __restrict__ b_hh2,   // [80]
    const float* __restrict__ W_out,   // [20]
    const float* __restrict__ b_out,   // [1]
    float* __restrict__ out,           // [5B | h0 | h1 | c0 | c1]
    int B)
{
    __shared__ __align__(16) float sWhh1[1600];
    __shared__ __align__(16) float sWih2[1600];
    __shared__ __align__(16) float sWhh2[1600];
    __shared__ __align__(16) float sIh1[160];   // packed [j][gate][col]
    __shared__ __align__(16) float sB1[80];     // packed [j][gate]
    __shared__ __align__(16) float sB2[80];     // packed [j][gate]
    __shared__ __align__(16) float sWout[HDIM];

    // ---- cooperative weight staging (packed layouts for 1x b128 per j) ----
    for (int i = threadIdx.x; i < 1600; i += 256) {
        sWhh1[i] = W_hh1[i];
        sWih2[i] = W_ih2[i];
        sWhh2[i] = W_hh2[i];
    }
    for (int i = threadIdx.x; i < 160; i += 256) {
        int j = i >> 3, r = i & 7, g = r >> 1, c = r & 1;
        sIh1[i] = W_ih1[(g * HDIM + j) * 2 + c];
    }
    for (int i = threadIdx.x; i < 80; i += 256) {
        int j = i >> 2, g = i & 3;
        int r = g * HDIM + j;
        sB1[i] = b_ih1[r] + b_hh1[r];
        sB2[i] = b_ih2[r] + b_hh2[r];
    }
    for (int i = threadIdx.x; i < HDIM; i += 256) sWout[i] = W_out[i];
    __syncthreads();

    const int tid = threadIdx.x;
    int bidx[M];
    bool val[M];
    #pragma unroll
    for (int m = 0; m < M; m++) {
        int b = blockIdx.x * (256 * M) + m * 256 + tid;
        val[m]  = (b < B);
        bidx[m] = val[m] ? b : 0;
    }
    const size_t BH = (size_t)B * HDIM;

    // ---- preproc ----
    float x0[M], x1[M];
    #pragma unroll
    for (int m = 0; m < M; m++) {
        float x  = inp[bidx[m]];
        float ax = fabsf(x);
        bool keep = ax >= 4.5399929762484854e-05f;             // expf(-10)
        // ln(y)/10 = log2(y) * (ln2/10)
        x0[m] = keep ? (__builtin_amdgcn_logf(ax + 1e-8f) * 0.069314718055994531f) : -1.0f;
        x1[m] = keep ? (x > 0.0f ? 1.0f : -1.0f) : (22026.465794806718f * x);
    }

    // ---- load layer-1 h_prev as pairs ----
    v2f hp[M][10];
    #pragma unroll
    for (int m = 0; m < M; m++) {
        const float4* h4 = (const float4*)(hidden + (size_t)bidx[m] * HDIM);
        #pragma unroll
        for (int k4 = 0; k4 < 5; k4++) {
            float4 hv = h4[k4];
            hp[m][2*k4]     = (v2f){hv.x, hv.y};
            hp[m][2*k4 + 1] = (v2f){hv.z, hv.w};
        }
    }

    // ---------------- LSTM layer 1 ----------------
    v2f ha[M][10];
    float4 cin[M], hob[M], cob[M];
    #pragma unroll
    for (int j = 0; j < HDIM; j++) {
        const int q = j & 3, g4 = j >> 2;
        if (q == 0) {   // stream c_prev in 4-wide chunks
            #pragma unroll
            for (int m = 0; m < M; m++)
                cin[m] = *(const float4*)(cell + (size_t)bidx[m] * HDIM + 4 * g4);
        }
        float4 p0 = *(const float4*)(sIh1 + 8 * j);
        float4 p1 = *(const float4*)(sIh1 + 8 * j + 4);
        float4 bb = *(const float4*)(sB1 + 4 * j);
        v2f ai[M], af[M], ag[M], ao[M];
        #pragma unroll
        for (int m = 0; m < M; m++) {
            ai[m] = (v2f){bb.x + x0[m]*p0.x + x1[m]*p0.y, 0.0f};
            af[m] = (v2f){bb.y + x0[m]*p0.z + x1[m]*p0.w, 0.0f};
            ag[m] = (v2f){bb.z + x0[m]*p1.x + x1[m]*p1.y, 0.0f};
            ao[m] = (v2f){bb.w + x0[m]*p1.z + x1[m]*p1.w, 0.0f};
        }
        const float* w = sWhh1 + j * HDIM;
        #pragma unroll
        for (int k4 = 0; k4 < 5; k4++) {
            float4 vi = *(const float4*)(w + 4*k4);
            float4 vf = *(const float4*)(w + 400 + 4*k4);
            float4 vg = *(const float4*)(w + 800 + 4*k4);
            float4 vo = *(const float4*)(w + 1200 + 4*k4);
            #pragma unroll
            for (int m = 0; m < M; m++) {
                v2f hlo = hp[m][2*k4], hhi = hp[m][2*k4+1];
                ai[m] = pkfma((v2f){vi.x, vi.y}, hlo, ai[m]);
                ai[m] = pkfma((v2f){vi.z, vi.w}, hhi, ai[m]);
                af[m] = pkfma((v2f){vf.x, vf.y}, hlo, af[m]);
                af[m] = pkfma((v2f){vf.z, vf.w}, hhi, af[m]);
                ag[m] = pkfma((v2f){vg.x, vg.y}, hlo, ag[m]);
                ag[m] = pkfma((v2f){vg.z, vg.w}, hhi, ag[m]);
                ao[m] = pkfma((v2f){vo.x, vo.y}, hlo, ao[m]);
                ao[m] = pkfma((v2f){vo.z, vo.w}, hhi, ao[m]);
            }
        }
        #pragma unroll
        for (int m = 0; m < M; m++) {
            float gi = ai[m].x + ai[m].y;
            float gf = af[m].x + af[m].y;
            float gg = ag[m].x + ag[m].y;
            float go = ao[m].x + ao[m].y;
            float cn = fsig(gf) * f4get(cin[m], q) + fsig(gi) * ftanh(gg);
            float hn = fsig(go) * ftanh(cn);
            ha[m][j >> 1][j & 1] = hn;
            f4set(cob[m], q, cn);
            f4set(hob[m], q, hn);
        }
        if (q == 3) {   // chunked stores of h0_new / c0_new
            #pragma unroll
            for (int m = 0; m < M; m++) if (val[m]) {
                size_t o0 = (size_t)NSTEP * B + (size_t)bidx[m] * HDIM + 4 * g4;
                *(float4*)(out + o0)           = hob[m];   // h0
                *(float4*)(out + o0 + 2 * BH)  = cob[m];   // c0
            }
        }
    }

    // ---- reload layer-2 h_prev ----
    #pragma unroll
    for (int m = 0; m < M; m++) {
        const float4* h4 = (const float4*)(hidden + BH + (size_t)bidx[m] * HDIM);
        #pragma unroll
        for (int k4 = 0; k4 < 5; k4++) {
            float4 hv = h4[k4];
            hp[m][2*k4]     = (v2f){hv.x, hv.y};
            hp[m][2*k4 + 1] = (v2f){hv.z, hv.w};
        }
    }

    float head[M];
    {
        float bo = b_out[0];
        #pragma unroll
        for (int m = 0; m < M; m++) head[m] = bo;
    }

    // ---------------- LSTM layer 2 ----------------
    #pragma unroll
    for (int j = 0; j < HDIM; j++) {
        const int q = j & 3, g4 = j >> 2;
        if (q == 0) {
            #pragma unroll
            for (int m = 0; m < M; m++)
                cin[m] = *(const float4*)(cell + BH + (size_t)bidx[m] * HDIM + 4 * g4);
        }
        float4 bb = *(const float4*)(sB2 + 4 * j);
        v2f ai[M], af[M], ag[M], ao[M];
        #pragma unroll
        for (int m = 0; m < M; m++) {
            ai[m] = (v2f){bb.x, 0.0f};
            af[m] = (v2f){bb.y, 0.0f};
            ag[m] = (v2f){bb.z, 0.0f};
            ao[m] = (v2f){bb.w, 0.0f};
        }
        const float* u = sWih2 + j * HDIM;
        const float* w = sWhh2 + j * HDIM;
        #pragma unroll
        for (int k4 = 0; k4 < 5; k4++) {
            float4 ui4 = *(const float4*)(u + 4*k4);
            float4 uf4 = *(const float4*)(u + 400 + 4*k4);
            float4 ug4 = *(const float4*)(u + 800 + 4*k4);
            float4 uo4 = *(const float4*)(u + 1200 + 4*k4);
            float4 wi4 = *(const float4*)(w + 4*k4);
            float4 wf4 = *(const float4*)(w + 400 + 4*k4);
            float4 wg4 = *(const float4*)(w + 800 + 4*k4);
            float4 wo4 = *(const float4*)(w + 1200 + 4*k4);
            #pragma unroll
            for (int m = 0; m < M; m++) {
                v2f alo = ha[m][2*k4], ahi = ha[m][2*k4+1];
                v2f hlo = hp[m][2*k4], hhi = hp[m][2*k4+1];
                ai[m] = pkfma((v2f){ui4.x, ui4.y}, alo, ai[m]);
                ai[m] = pkfma((v2f){ui4.z, ui4.w}, ahi, ai[m]);
                af[m] = pkfma((v2f){uf4.x, uf4.y}, alo, af[m]);
                af[m] = pkfma((v2f){uf4.z, uf4.w}, ahi, af[m]);
                ag[m] = pkfma((v2f){ug4.x, ug4.y}, alo, ag[m]);
                ag[m] = pkfma((v2f){ug4.z, ug4.w}, ahi, ag[m]);
                ao[m] = pkfma((v2f){uo4.x, uo4.y}, alo, ao[m]);
                ao[m] = pkfma((v2f){uo4.z, uo4.w}, ahi, ao[m]);
                ai[m] = pkfma((v2f){wi4.x, wi4.y}, hlo, ai[m]);
                ai[m] = pkfma((v2f){wi4.z, wi4.w}, hhi, ai[m]);
                af[m] = pkfma((v2f){wf4.x, wf4.y}, hlo, af[m]);
                af[m] = pkfma((v2f){wf4.z, wf4.w}, hhi, af[m]);
                ag[m] = pkfma((v2f){wg4.x, wg4.y}, hlo, ag[m]);
                ag[m] = pkfma((v2f){wg4.z, wg4.w}, hhi, ag[m]);
                ao[m] = pkfma((v2f){wo4.x, wo4.y}, hlo, ao[m]);
                ao[m] = pkfma((v2f){wo4.z, wo4.w}, hhi, ao[m]);
            }
        }
        float wout = sWout[j];
        #pragma unroll
        for (int m = 0; m < M; m++) {
            float gi = ai[m].x + ai[m].y;
            float gf = af[m].x + af[m].y;
            float gg = ag[m].x + ag[m].y;
            float go = ao[m].x + ao[m].y;
            float cn = fsig(gf) * f4get(cin[m], q) + fsig(gi) * ftanh(gg);
            float hn = fsig(go) * ftanh(cn);
            head[m] = fmaf(hn, wout, head[m]);
            f4set(cob[m], q, cn);
            f4set(hob[m], q, hn);
        }
        if (q == 3) {   // chunked stores of h1_new / c1_new
            #pragma unroll
            for (int m = 0; m < M; m++) if (val[m]) {
                size_t o1 = (size_t)NSTEP * B + BH + (size_t)bidx[m] * HDIM + 4 * g4;
                *(float4*)(out + o1)           = hob[m];   // h1
                *(float4*)(out + o1 + 2 * BH)  = cob[m];   // c1
            }
        }
    }

    // ---- output head: (h1 . W_out + b_out) * [1..5] ----
    #pragma unroll
    for (int m = 0; m < M; m++) if (val[m]) {
        float a = head[m];
        float* o = out + (size_t)bidx[m] * NSTEP;
        o[0] = a; o[1] = 2.0f*a; o[2] = 3.0f*a; o[3] = 4.0f*a; o[4] = 5.0f*a;
    }
}

extern "C" void kernel_launch(void* const* d_in, const int* in_sizes, int n_in,
                              void* d_out, int out_size, void* d_ws, size_t ws_size,
                              hipStream_t stream) {
    const float* inp    = (const float*)d_in[0];
    const float* hidden = (const float*)d_in[1];
    const float* cell   = (const float*)d_in[2];
    const float* W_ih1  = (const float*)d_in[3];
    const float* W_hh1  = (const float*)d_in[4];
    const float* b_ih1  = (const float*)d_in[5];
    const float* b_hh1  = (const float*)d_in[6];
    const float* W_ih2  = (const float*)d_in[7];
    const float* W_hh2  = (const float*)d_in[8];
    const float* b_ih2  = (const float*)d_in[9];
    const float* b_hh2  = (const float*)d_in[10];
    const float* W_out  = (const float*)d_in[11];
    const float* b_out  = (const float*)d_in[12];
    float* out = (float*)d_out;

    int B = in_sizes[0];
    int grid = (B + 256 * M - 1) / (256 * M);
    navi_kernel<<<grid, 256, 0, stream>>>(
        inp, hidden, cell,
        W_ih1, W_hh1, b_ih1, b_hh1,
        W_ih2, W_hh2, b_ih2, b_hh2,
        W_out, b_out, out, B);
}

// Round 2
// 993.553 us; speedup vs baseline: 2.0453x; 2.0453x over previous
//
#include <hip/hip_runtime.h>

#define HDIM 20
#define NSTEP 5

// Constant-address-space pointer: uniform loads through this are selected as
// s_load (SMEM) -> weights live in SGPRs, FMAs read them as scalar operands.
typedef float __attribute__((address_space(4))) cfloat;
__device__ __forceinline__ const cfloat* cptr(const void* p) {
    return (const cfloat*)(unsigned long long)p;
}

__device__ __forceinline__ float fsig(float x) {
    // 1/(1+e^-x) via v_exp_f32 (2^x) + v_rcp_f32
    return __builtin_amdgcn_rcpf(1.0f + __builtin_amdgcn_exp2f(-1.4426950408889634f * x));
}
__device__ __forceinline__ float ftanh(float x) {
    // 1 - 2/(e^{2x}+1); saturates correctly at +/-inf
    return 1.0f - 2.0f * __builtin_amdgcn_rcpf(__builtin_amdgcn_exp2f(2.8853900817779268f * x) + 1.0f);
}

__global__ __launch_bounds__(256) void navi_kernel(
    const float* __restrict__ inp,     // [B]
    const float* __restrict__ hidden,  // [2,B,H]
    const float* __restrict__ cell,    // [2,B,H]
    const float* __restrict__ W_ih1,   // [80,2]
    const float* __restrict__ W_hh1,   // [80,20]
    const float* __restrict__ b_ih1,   // [80]
    const float* __restrict__ b_hh1,   // [80]
    const float* __restrict__ W_ih2,   // [80,20]
    const float* __restrict__ W_hh2,   // [80,20]
    const float* __restrict__ b_ih2,   // [80]
    const float* __restrict__ b_hh2,   // [80]
    const float* __restrict__ W_out,   // [20]
    const float* __restrict__ b_out,   // [1]
    float* __restrict__ out,           // [5B | h0 | h1 | c0 | c1]
    int B)
{
    const int b = blockIdx.x * 256 + threadIdx.x;
    if (b >= B) return;

    const cfloat* wih1 = cptr(W_ih1);
    const cfloat* whh1 = cptr(W_hh1);
    const cfloat* bi1  = cptr(b_ih1);
    const cfloat* bh1  = cptr(b_hh1);
    const cfloat* wih2 = cptr(W_ih2);
    const cfloat* whh2 = cptr(W_hh2);
    const cfloat* bi2  = cptr(b_ih2);
    const cfloat* bh2  = cptr(b_hh2);
    const cfloat* wout = cptr(W_out);
    const cfloat* bo   = cptr(b_out);

    const size_t BH = (size_t)B * HDIM;

    // ---- preproc ----
    float x = inp[b];
    float ax = fabsf(x);
    bool keep = ax >= 4.5399929762484854e-05f;              // expf(-10)
    // ln(y)/10 = log2(y) * (ln2/10)
    float x0 = keep ? (__builtin_amdgcn_logf(ax + 1e-8f) * 0.069314718055994531f) : -1.0f;
    float x1 = keep ? (x > 0.0f ? 1.0f : -1.0f) : (22026.465794806718f * x);

    // ---- load h0_prev, c0_prev (float4 x5; b*80B is 16B aligned) ----
    float hp[HDIM], cp[HDIM];
    {
        const float4* h4 = (const float4*)(hidden + (size_t)b * HDIM);
        const float4* c4 = (const float4*)(cell   + (size_t)b * HDIM);
        #pragma unroll
        for (int k4 = 0; k4 < 5; k4++) {
            float4 hv = h4[k4];
            float4 cv = c4[k4];
            hp[k4*4+0] = hv.x; hp[k4*4+1] = hv.y; hp[k4*4+2] = hv.z; hp[k4*4+3] = hv.w;
            cp[k4*4+0] = cv.x; cp[k4*4+1] = cv.y; cp[k4*4+2] = cv.z; cp[k4*4+3] = cv.w;
        }
    }

    // ---------------- LSTM layer 1 (weights from SGPRs) ----------------
    float ha[HDIM];
    #pragma unroll
    for (int j = 0; j < HDIM; j++) {
        float gi = bi1[j]      + bh1[j]      + x0 * wih1[2*j]          + x1 * wih1[2*j+1];
        float gf = bi1[j + 20] + bh1[j + 20] + x0 * wih1[2*(j+20)]     + x1 * wih1[2*(j+20)+1];
        float gg = bi1[j + 40] + bh1[j + 40] + x0 * wih1[2*(j+40)]     + x1 * wih1[2*(j+40)+1];
        float go = bi1[j + 60] + bh1[j + 60] + x0 * wih1[2*(j+60)]     + x1 * wih1[2*(j+60)+1];
        #pragma unroll
        for (int k = 0; k < HDIM; k++) {
            float h = hp[k];
            gi = fmaf(whh1[(j     ) * HDIM + k], h, gi);
            gf = fmaf(whh1[(j + 20) * HDIM + k], h, gf);
            gg = fmaf(whh1[(j + 40) * HDIM + k], h, gg);
            go = fmaf(whh1[(j + 60) * HDIM + k], h, go);
        }
        float cn = fsig(gf) * cp[j] + fsig(gi) * ftanh(gg);
        cp[j] = cn;                           // c0_new
        ha[j] = fsig(go) * ftanh(cn);         // h0_new
    }

    // ---- store h0_new, c0_new ----
    const size_t oh0 = (size_t)NSTEP * B + (size_t)b * HDIM;
    const size_t oh1 = oh0 + BH;
    const size_t oc0 = oh1 + BH;
    const size_t oc1 = oc0 + BH;
    {
        float4* oH = (float4*)(out + oh0);
        float4* oC = (float4*)(out + oc0);
        #pragma unroll
        for (int k4 = 0; k4 < 5; k4++) {
            oH[k4] = make_float4(ha[k4*4+0], ha[k4*4+1], ha[k4*4+2], ha[k4*4+3]);
            oC[k4] = make_float4(cp[k4*4+0], cp[k4*4+1], cp[k4*4+2], cp[k4*4+3]);
        }
    }

    // ---- load h1_prev, c1_prev ----
    {
        const float4* h4 = (const float4*)(hidden + BH + (size_t)b * HDIM);
        const float4* c4 = (const float4*)(cell   + BH + (size_t)b * HDIM);
        #pragma unroll
        for (int k4 = 0; k4 < 5; k4++) {
            float4 hv = h4[k4];
            float4 cv = c4[k4];
            hp[k4*4+0] = hv.x; hp[k4*4+1] = hv.y; hp[k4*4+2] = hv.z; hp[k4*4+3] = hv.w;
            cp[k4*4+0] = cv.x; cp[k4*4+1] = cv.y; cp[k4*4+2] = cv.z; cp[k4*4+3] = cv.w;
        }
    }

    // ---------------- LSTM layer 2 (input = ha) ----------------
    float head = bo[0];
    float hb[HDIM];
    #pragma unroll
    for (int j = 0; j < HDIM; j++) {
        float gi = bi2[j]      + bh2[j];
        float gf = bi2[j + 20] + bh2[j + 20];
        float gg = bi2[j + 40] + bh2[j + 40];
        float go = bi2[j + 60] + bh2[j + 60];
        #pragma unroll
        for (int k = 0; k < HDIM; k++) {
            float a = ha[k];
            gi = fmaf(wih2[(j     ) * HDIM + k], a, gi);
            gf = fmaf(wih2[(j + 20) * HDIM + k], a, gf);
            gg = fmaf(wih2[(j + 40) * HDIM + k], a, gg);
            go = fmaf(wih2[(j + 60) * HDIM + k], a, go);
        }
        #pragma unroll
        for (int k = 0; k < HDIM; k++) {
            float h = hp[k];
            gi = fmaf(whh2[(j     ) * HDIM + k], h, gi);
            gf = fmaf(whh2[(j + 20) * HDIM + k], h, gf);
            gg = fmaf(whh2[(j + 40) * HDIM + k], h, gg);
            go = fmaf(whh2[(j + 60) * HDIM + k], h, go);
        }
        float cn = fsig(gf) * cp[j] + fsig(gi) * ftanh(gg);
        float hn = fsig(go) * ftanh(cn);
        cp[j] = cn;                           // c1_new
        hb[j] = hn;                           // h1_new
        head = fmaf(hn, wout[j], head);
    }

    // ---- store h1_new, c1_new ----
    {
        float4* oH = (float4*)(out + oh1);
        float4* oC = (float4*)(out + oc1);
        #pragma unroll
        for (int k4 = 0; k4 < 5; k4++) {
            oH[k4] = make_float4(hb[k4*4+0], hb[k4*4+1], hb[k4*4+2], hb[k4*4+3]);
            oC[k4] = make_float4(cp[k4*4+0], cp[k4*4+1], cp[k4*4+2], cp[k4*4+3]);
        }
    }

    // ---- output head: (h1 . W_out + b_out) * [1..5] ----
    float* o = out + (size_t)b * NSTEP;
    o[0] = head;
    o[1] = 2.0f * head;
    o[2] = 3.0f * head;
    o[3] = 4.0f * head;
    o[4] = 5.0f * head;
}

extern "C" void kernel_launch(void* const* d_in, const int* in_sizes, int n_in,
                              void* d_out, int out_size, void* d_ws, size_t ws_size,
                              hipStream_t stream) {
    const float* inp    = (const float*)d_in[0];
    const float* hidden = (const float*)d_in[1];
    const float* cell   = (const float*)d_in[2];
    const float* W_ih1  = (const float*)d_in[3];
    const float* W_hh1  = (const float*)d_in[4];
    const float* b_ih1  = (const float*)d_in[5];
    const float* b_hh1  = (const float*)d_in[6];
    const float* W_ih2  = (const float*)d_in[7];
    const float* W_hh2  = (const float*)d_in[8];
    const float* b_ih2  = (const float*)d_in[9];
    const float* b_hh2  = (const float*)d_in[10];
    const float* W_out  = (const float*)d_in[11];
    const float* b_out  = (const float*)d_in[12];
    float* out = (float*)d_out;

    int B = in_sizes[0];
    int grid = (B + 255) / 256;
    navi_kernel<<<grid, 256, 0, stream>>>(
        inp, hidden, cell,
        W_ih1, W_hh1, b_ih1, b_hh1,
        W_ih2, W_hh2, b_ih2, b_hh2,
        W_out, b_out, out, B);
}